// Round 2
// 83.707 us; speedup vs baseline: 1.0085x; 1.0085x over previous
//
#include <hip/hip_runtime.h>

#define BB 4
#define HH 480
#define WW 640

// cheap reciprocal of a double: f32 seed, ~1e-5 relative error.
// Valid where the use is scale-invariant or self-correcting (Newton).
__device__ __forceinline__ double crcp(double d) {
    return (double)__builtin_amdgcn_rcpf((float)d);
}

__global__ __launch_bounds__(256) void d2n_kernel(const float* __restrict__ pts,
                                                  float* __restrict__ out) {
    int idx = blockIdx.x * 256 + threadIdx.x;
    if (idx >= BB * HH * WW) return;
    int x = idx % WW;
    int t1 = idx / WW;
    int y = t1 % HH;
    int b = t1 / HH;

    const size_t HW = (size_t)HH * WW;
    const float* xs = pts + ((size_t)b * 3 + 0) * HW;
    const float* ys = pts + ((size_t)b * 3 + 1) * HW;
    const float* zs = pts + ((size_t)b * 3 + 2) * HW;

    // ---- Branch-free stencil: clamped addresses, all 27 loads in flight ----
    int row[3], col[3];
    bool rin[3], cin[3];
#pragma unroll
    for (int k = 0; k < 3; ++k) {
        int yy = y + k - 1, xx = x + k - 1;
        rin[k] = (unsigned)yy < HH;
        cin[k] = (unsigned)xx < WW;
        row[k] = min(max(yy, 0), HH - 1) * WW;
        col[k] = min(max(xx, 0), WW - 1);
    }
    float px[9], py[9], pz[9];
    bool inb[9];
#pragma unroll
    for (int i = 0; i < 9; ++i) {
        int r = i / 3, c = i % 3;
        int o = row[r] + col[c];
        inb[i] = rin[r] & cin[c];
        pz[i] = zs[o];
        px[i] = xs[o];
        py[i] = ys[o];
    }

    // ---- Gram accumulation (f32, matches reference AtA precision) ----
    float sxx = 0.f, sxy = 0.f, sxz = 0.f, sx = 0.f;
    float syy = 0.f, syz = 0.f, sy = 0.f;
    float szz = 0.f, sz = 0.f, cnt = 0.f;
#pragma unroll
    for (int i = 0; i < 9; ++i) {
        float w = (inb[i] && pz[i] > 0.0f && pz[i] < 10.0f) ? 1.0f : 0.0f;
        float qx = px[i] * w, qy = py[i] * w, qz = pz[i] * w;
        sxx += qx * px[i]; sxy += qx * py[i]; sxz += qx * pz[i]; sx += qx;
        syy += qy * py[i]; syz += qy * pz[i]; sy += qy;
        szz += qz * pz[i]; sz += qz;
        cnt += w;
    }

    // ---- Promote to f64; scale by ~1/trace (uniform scale: eigvec-invariant) ----
    double tr = (double)sxx + (double)syy + (double)szz + (double)cnt;
    double it = crcp(tr);
    double m00 = sxx * it, m01 = sxy * it, m02 = sxz * it, m03 = sx * it;
    double m11 = syy * it, m12 = syz * it, m13 = sy * it;
    double m22 = szz * it, m23 = sz * it, m33 = cnt * it;

    // ---- Characteristic polynomial via shared 2x2 row-pair minors (f64).
    //      N01_* = minors of rows (0,1) of M; N23_* = rows (2,3).
    //      (verified term-by-term + on diag(1,2,3,4): e=10,35,50,24) ----
    double N01_01 = m00 * m11 - m01 * m01;
    double N01_02 = m00 * m12 - m02 * m01;
    double N01_03 = m00 * m13 - m03 * m01;
    double N01_12 = m01 * m12 - m02 * m11;
    double N01_13 = m01 * m13 - m03 * m11;
    double Ncross = m02 * m13 - m03 * m12;   // = N01_23 = N23_01 (symmetry)
    double N23_02 = m02 * m23 - m22 * m03;
    double N23_03 = m02 * m33 - m23 * m03;
    double N23_12 = m12 * m23 - m22 * m13;
    double N23_13 = m12 * m33 - m23 * m13;
    double N23_23 = m22 * m33 - m23 * m23;

    double e1 = (m00 + m11) + (m22 + m33);
    double e2 = (N01_01 + N23_23)
              + ((m00 * m22 - m02 * m02) + (m00 * m33 - m03 * m03))
              + ((m11 * m22 - m12 * m12) + (m11 * m33 - m13 * m13));
    double P0 = m11 * N23_23 - m12 * N23_13 + m13 * N23_12;  // minor {1,2,3}
    double P1 = m00 * N23_23 - m02 * N23_03 + m03 * N23_02;  // minor {0,2,3}
    double P2 = m03 * N01_13 - m13 * N01_03 + m33 * N01_01;  // minor {0,1,3}
    double P3 = m02 * N01_12 - m12 * N01_02 + m22 * N01_01;  // minor {0,1,2}
    double e3 = (P0 + P1) + (P2 + P3);
    double e4 = N01_01 * N23_23 - N01_02 * N23_13 + N01_03 * N23_12
              + N01_12 * N23_03 - N01_13 * N23_02 + Ncross * Ncross;

    // ---- Newton toward smallest eigenvalue: 8 f32 warm iters + 4 f64 polish.
    //      From lam=0: p>0, p'<0 -> monotone. ----
    float e1f = (float)e1, e2f = (float)e2, e3f = (float)e3, e4f = (float)e4;
    float t31f = 3.0f * e1f, t22f = 2.0f * e2f;
    float lf = 0.0f;
#pragma unroll
    for (int itn = 0; itn < 8; ++itn) {
        float p  = (((lf - e1f) * lf + e2f) * lf - e3f) * lf + e4f;
        float dp = ((4.0f * lf - t31f) * lf + t22f) * lf - e3f;
        dp = fminf(dp, -1e-30f);
        lf = lf - p * __builtin_amdgcn_rcpf(dp);
        lf = fminf(fmaxf(lf, 0.0f), 0.26f);
    }
    double t31 = 3.0 * e1, t22 = 2.0 * e2;
    double lam = (double)lf;
#pragma unroll
    for (int itn = 0; itn < 4; ++itn) {
        double p  = (((lam - e1) * lam + e2) * lam - e3) * lam + e4;
        double dp = ((4.0 * lam - t31) * lam + t22) * lam - e3;
        dp = fmin(dp, -1e-30);
        lam = lam - p * crcp(dp);  // 1e-5-accurate step: self-correcting
        lam = fmin(fmax(lam, 0.0), 0.26);
    }

    // ---- Adjugate of B = M - lam I via shared Laplace 2x2 minors.
    //      s-set = minors of rows (0,1) of B, c-set = rows (2,3); c0 = s5.
    //      adj is symmetric rank-1 = c * v1 v1^T; select column by largest
    //      |diagonal| (max diag = c*v_max^2 >= c/4: robust for ANY eigvec).
    //      (formulas verified on diag(2,3,4,5) -> adj=(60,40,30,24)) ----
    double d0 = m00 - lam, d1 = m11 - lam, d2 = m22 - lam, d3 = m33 - lam;
    double s0 = d0 * d1 - m01 * m01;
    double s1 = d0 * m12 - m01 * m02;
    double s2 = d0 * m13 - m01 * m03;
    double s3 = m01 * m12 - d1 * m02;
    double s4 = m01 * m13 - d1 * m03;
    double s5 = m02 * m13 - m12 * m03;   // = c0 by symmetry
    double c1 = m02 * m23 - m03 * d2;
    double c2 = m02 * d3 - m03 * m23;
    double c3 = m12 * m23 - m13 * d2;
    double c4 = m12 * d3 - m13 * m23;
    double c5 = d2 * d3 - m23 * m23;

    double adj00 =  d1 * c5 - m12 * c4 + m13 * c3;
    double adj01 = -m01 * c5 + m02 * c4 - m03 * c3;
    double adj02 =  m13 * s5 - m23 * s4 + d3 * s3;
    double adj03 = -m12 * s5 + d2 * s4 - m23 * s3;
    double adj11 =  d0 * c5 - m02 * c2 + m03 * c1;
    double adj12 = -m03 * s5 + m23 * s2 - d3 * s1;
    double adj13 =  m02 * s5 - d2 * s2 + m23 * s1;
    double adj22 =  m03 * s4 - m13 * s2 + d3 * s0;
    double adj23 = -m02 * s4 + m12 * s2 - m23 * s0;
    double adj33 =  m02 * s3 - m12 * s1 + d2 * s0;

    // pick column with largest |diagonal| (= largest v1 comp^2)
    double best = fabs(adj00);
    double vx = adj00, vy = adj01, vz = adj02, vd = adj00;
    double a1 = fabs(adj11);
    if (a1 > best) { best = a1; vx = adj01; vy = adj11; vz = adj12; vd = adj11; }
    double a2 = fabs(adj22);
    if (a2 > best) { best = a2; vx = adj02; vy = adj12; vz = adj22; vd = adj22; }
    double a3 = fabs(adj33);
    if (a3 > best) { best = a3; vx = adj03; vy = adj13; vz = adj23; vd = adj33; }

    // scale column by ~1/vd (uniform scale of the eigvec: error cancels in
    // the f32 normalization below), then finish in f32
    double sc = crcp(vd);
    float fx = (float)(vx * sc), fy = (float)(vy * sc), fz = (float)(vz * sc);

    float nd = fx * fx + fy * fy + fz * fz;
    float inv = __builtin_amdgcn_rsqf(fmaxf(nd, 1e-30f));
    float nx = fx * inv, ny = fy * inv, nz = fz * inv;

    int o = y * WW + x;
    float cx = px[4], cy = py[4], cz = pz[4];
    float dot = nx * cx + ny * cy + nz * cz;
    float sgn = (dot > 0.0f) ? 1.0f : ((dot < 0.0f) ? -1.0f : 0.0f);
    nx *= sgn; ny *= sgn; nz *= sgn;

    out[((size_t)b * 3 + 0) * HW + o] = nx;
    out[((size_t)b * 3 + 1) * HW + o] = ny;
    out[((size_t)b * 3 + 2) * HW + o] = nz;

    bool cvalid = (cz > 0.0f && cz < 10.0f);
    bool m = cvalid && (cnt >= 4.0f) && (nx * nx + ny * ny + nz * nz > 0.25f);
    out[(size_t)BB * 3 * HW + (size_t)b * HW + o] = m ? 1.0f : 0.0f;
}

extern "C" void kernel_launch(void* const* d_in, const int* in_sizes, int n_in,
                              void* d_out, int out_size, void* d_ws, size_t ws_size,
                              hipStream_t stream) {
    const float* pts = (const float*)d_in[0];
    float* out = (float*)d_out;
    int total = BB * HH * WW;
    d2n_kernel<<<(total + 255) / 256, 256, 0, stream>>>(pts, out);
}